// Round 1
// baseline (409.139 us; speedup 1.0000x reference)
//
#include <hip/hip_runtime.h>

#define WW 1024
#define HH 1024
#define NIMG 2
#define NCH 8
#define HWSZ (HH * WW)
#define CHW (NCH * HWSZ)

// reflect index into [0, HH) for t in [-16, HH+16)
__device__ __forceinline__ int reflect_idx(int t) {
    if (t < 0) t = -t;
    if (t > HH - 1) t = 2 * (HH - 1) - t;
    return t;
}

// LDS granule swizzle: permute 16B granules so stride-32B wave accesses are bank-balanced
__device__ __forceinline__ int swz(int g) { return g ^ ((g >> 3) & 7); }

__global__ void k_init(unsigned* wsU) {
    wsU[0] = 0x7f800000u; // running min bits (+inf)
    wsU[1] = 0u;          // running max bits (diff >= 0 so uint-ordered)
    wsU[2] = 0u;          // masked sum (float 0.0)
    wsU[3] = 0u;          // masked count (float 0.0)
}

template <bool STORE>
__global__ __launch_bounds__(256) void k_mask(const float* __restrict__ msO,
                                              const float* __restrict__ pan,
                                              unsigned* __restrict__ wsU,
                                              float* __restrict__ diffArr) {
    int gid = blockIdx.x * 256 + threadIdx.x;
    int base = gid * 4; // [0, 2M)
    int n = base >> 20;
    int hw = base & (HWSZ - 1);
    const float* po = msO + n * CHW + hw;
    float sx = 0.f, sy = 0.f, sz = 0.f, sw = 0.f;
#pragma unroll
    for (int c = 0; c < NCH; ++c) {
        float4 v = *(const float4*)(po + c * HWSZ);
        sx += v.x; sy += v.y; sz += v.z; sw += v.w;
    }
    float4 pv = *(const float4*)(pan + n * HWSZ + hw);
    float4 d;
    d.x = fabsf(sx * 0.125f - pv.x);
    d.y = fabsf(sy * 0.125f - pv.y);
    d.z = fabsf(sz * 0.125f - pv.z);
    d.w = fabsf(sw * 0.125f - pv.w);
    if (STORE) *(float4*)(diffArr + base) = d;

    float m = fminf(fminf(d.x, d.y), fminf(d.z, d.w));
    float M = fmaxf(fmaxf(d.x, d.y), fmaxf(d.z, d.w));
#pragma unroll
    for (int off = 32; off > 0; off >>= 1) {
        m = fminf(m, __shfl_down(m, off));
        M = fmaxf(M, __shfl_down(M, off));
    }
    __shared__ float sm[4], sM[4];
    int wid = threadIdx.x >> 6, lane = threadIdx.x & 63;
    if (lane == 0) { sm[wid] = m; sM[wid] = M; }
    __syncthreads();
    if (threadIdx.x == 0) {
        m = fminf(fminf(sm[0], sm[1]), fminf(sm[2], sm[3]));
        M = fmaxf(fmaxf(sM[0], sM[1]), fmaxf(sM[2], sM[3]));
        atomicMin(wsU + 0, __float_as_uint(m));
        atomicMax(wsU + 1, __float_as_uint(M));
    }
}

// Main kernel: block = 128 threads = one image row; each thread owns 8 pixels.
// LDS stages the 8 channels of one reflected target row (1056 cols incl. 16+16 halo),
// granule-swizzled. Per (di): stage; per (c): read 40-float segment, accumulate
// acc[dj][p] += |ms - seg|; after c-loop fold min over dj.
template <bool USE_DIFF>
__global__ __launch_bounds__(128, 2) void k_main(const float* __restrict__ ms,
                                                 const float* __restrict__ tgt,
                                                 const float* __restrict__ msO,
                                                 const float* __restrict__ pan,
                                                 const float* __restrict__ diffArr,
                                                 unsigned* __restrict__ wsU) {
    __shared__ float lds[8 * 1056]; // 8 channel-rows x (1024+32) floats, swizzled granules
    const int tid = threadIdx.x;    // 0..127
    const int n = blockIdx.x >> 10;
    const int h = blockIdx.x & (HH - 1);
    const int w0 = tid * 8;

    // ms fragment: 8 channels x 8 pixels, kept in registers
    const float* msBase = ms + n * CHW + h * WW + w0;
    float msv[8][8];
#pragma unroll
    for (int c = 0; c < NCH; ++c) {
        float4 a = *(const float4*)(msBase + c * HWSZ);
        float4 b = *(const float4*)(msBase + c * HWSZ + 4);
        msv[c][0] = a.x; msv[c][1] = a.y; msv[c][2] = a.z; msv[c][3] = a.w;
        msv[c][4] = b.x; msv[c][5] = b.y; msv[c][6] = b.z; msv[c][7] = b.w;
    }

    // Precompute swizzled LDS offsets (constant across di / c)
    int segOff[10]; // read offsets: granule 2*tid+q
#pragma unroll
    for (int q = 0; q < 10; ++q) segOff[q] = swz(2 * tid + q) * 4;
    const int wOff0 = swz(4 + tid) * 4;   // staging write, q even (cols tid*4)
    const int wOff1 = swz(132 + tid) * 4; // staging write, q odd (cols 512+tid*4)
    // edge staging precompute (2 scalars per thread)
    int eC[2], eFidx[2], eGcol[2];
#pragma unroll
    for (int e = 0; e < 2; ++e) {
        int id = tid * 2 + e;
        eC[e] = id >> 5;
        int k = id & 31;
        if (k < 16) { eFidx[e] = k; eGcol[e] = 16 - k; }
        else        { int k2 = k - 16; eFidx[e] = 1040 + k2; eGcol[e] = 1022 - k2; }
    }

    float minv[8];
#pragma unroll
    for (int p = 0; p < 8; ++p) minv[p] = 3.0e38f;

    const float* tgtN = tgt + n * CHW;

    for (int di = 0; di < 9; ++di) {
        int gr = reflect_idx(h + (di - 4) * 4);
        __syncthreads(); // protect previous iteration's LDS reads
        // middle: 8 rows x 256 float4; thread does cols [tid*4) and [512+tid*4) of each channel
        const float* rowBase = tgtN + gr * WW + tid * 4;
#pragma unroll
        for (int c = 0; c < NCH; ++c) {
            float4 v0 = *(const float4*)(rowBase + c * HWSZ);
            float4 v1 = *(const float4*)(rowBase + c * HWSZ + 512);
            *(float4*)&lds[c * 1056 + wOff0] = v0;
            *(float4*)&lds[c * 1056 + wOff1] = v1;
        }
        // edges: 8 rows x 32 scalars = 256, 2 per thread
#pragma unroll
        for (int e = 0; e < 2; ++e) {
            float v = tgtN[eC[e] * HWSZ + gr * WW + eGcol[e]];
            int fidx = eFidx[e];
            lds[eC[e] * 1056 + swz(fidx >> 2) * 4 + (fidx & 3)] = v;
        }
        __syncthreads();

        float acc[9][8];
#pragma unroll
        for (int c = 0; c < NCH; ++c) {
            float seg[40];
#pragma unroll
            for (int q = 0; q < 10; ++q) {
                float4 v = *(const float4*)&lds[c * 1056 + segOff[q]];
                seg[q * 4 + 0] = v.x; seg[q * 4 + 1] = v.y;
                seg[q * 4 + 2] = v.z; seg[q * 4 + 3] = v.w;
            }
            if (c == 0) {
#pragma unroll
                for (int dj = 0; dj < 9; ++dj)
#pragma unroll
                    for (int p = 0; p < 8; ++p)
                        acc[dj][p] = fabsf(msv[0][p] - seg[p + dj * 4]);
            } else {
#pragma unroll
                for (int dj = 0; dj < 9; ++dj)
#pragma unroll
                    for (int p = 0; p < 8; ++p)
                        acc[dj][p] += fabsf(msv[c][p] - seg[p + dj * 4]);
            }
        }
#pragma unroll
        for (int dj = 0; dj < 9; ++dj)
#pragma unroll
            for (int p = 0; p < 8; ++p)
                minv[p] = fminf(minv[p], acc[dj][p]);
    }

    // mask + block reduction
    float lo = __uint_as_float(wsU[0]);
    float hi = __uint_as_float(wsU[1]);
    float thresh = lo + (hi - lo) * (10.0f / 255.0f);

    float dv[8];
    if (USE_DIFF) {
        const float* dp = diffArr + n * HWSZ + h * WW + w0;
        float4 a = *(const float4*)dp;
        float4 b = *(const float4*)(dp + 4);
        dv[0] = a.x; dv[1] = a.y; dv[2] = a.z; dv[3] = a.w;
        dv[4] = b.x; dv[5] = b.y; dv[6] = b.z; dv[7] = b.w;
    } else {
        const float* po = msO + n * CHW + h * WW + w0;
        float s[8];
#pragma unroll
        for (int p = 0; p < 8; ++p) s[p] = 0.f;
#pragma unroll
        for (int c = 0; c < NCH; ++c) {
            float4 a = *(const float4*)(po + c * HWSZ);
            float4 b = *(const float4*)(po + c * HWSZ + 4);
            s[0] += a.x; s[1] += a.y; s[2] += a.z; s[3] += a.w;
            s[4] += b.x; s[5] += b.y; s[6] += b.z; s[7] += b.w;
        }
        const float* pp = pan + n * HWSZ + h * WW + w0;
        float4 pa = *(const float4*)pp;
        float4 pb = *(const float4*)(pp + 4);
        float pvv[8] = {pa.x, pa.y, pa.z, pa.w, pb.x, pb.y, pb.z, pb.w};
#pragma unroll
        for (int p = 0; p < 8; ++p) dv[p] = fabsf(s[p] * 0.125f - pvv[p]);
    }

    float lsum = 0.f, lcnt = 0.f;
#pragma unroll
    for (int p = 0; p < 8; ++p) {
        if (dv[p] > thresh) { lsum += minv[p]; lcnt += 1.f; }
    }
#pragma unroll
    for (int off = 32; off > 0; off >>= 1) {
        lsum += __shfl_down(lsum, off);
        lcnt += __shfl_down(lcnt, off);
    }
    __shared__ float rs[2], rc[2];
    int wid = tid >> 6, lane = tid & 63;
    if (lane == 0) { rs[wid] = lsum; rc[wid] = lcnt; }
    __syncthreads();
    if (tid == 0) {
        atomicAdd((float*)(wsU + 2), rs[0] + rs[1]);
        atomicAdd((float*)(wsU + 3), rc[0] + rc[1]);
    }
}

__global__ void k_fin(const unsigned* __restrict__ wsU, float* __restrict__ out) {
    float sum = __uint_as_float(wsU[2]);
    float cnt = __uint_as_float(wsU[3]);
    out[0] = (cnt > 0.f) ? (sum / fmaxf(cnt, 1.f)) : 0.f;
}

extern "C" void kernel_launch(void* const* d_in, const int* in_sizes, int n_in,
                              void* d_out, int out_size, void* d_ws, size_t ws_size,
                              hipStream_t stream) {
    const float* ms  = (const float*)d_in[0];
    const float* tgt = (const float*)d_in[1];
    const float* msO = (const float*)d_in[2];
    const float* pan = (const float*)d_in[3];
    float* out = (float*)d_out;
    unsigned* wsU = (unsigned*)d_ws;
    float* diffArr = (float*)d_ws + 64;

    const size_t needWs = 64u * 4u + (size_t)NIMG * HWSZ * 4u;
    const bool useDiff = ws_size >= needWs;

    k_init<<<1, 1, 0, stream>>>(wsU);
    if (useDiff) {
        k_mask<true><<<(NIMG * HWSZ / 4 + 255) / 256, 256, 0, stream>>>(msO, pan, wsU, diffArr);
        k_main<true><<<NIMG * HH, 128, 0, stream>>>(ms, tgt, msO, pan, diffArr, wsU);
    } else {
        k_mask<false><<<(NIMG * HWSZ / 4 + 255) / 256, 256, 0, stream>>>(msO, pan, wsU, nullptr);
        k_main<false><<<NIMG * HH, 128, 0, stream>>>(ms, tgt, msO, pan, nullptr, wsU);
    }
    k_fin<<<1, 1, 0, stream>>>(wsU, out);
}

// Round 3
// 331.184 us; speedup vs baseline: 1.2354x; 1.2354x over previous
//
#include <hip/hip_runtime.h>
#include <hip/hip_fp16.h>

#define WW 1024
#define HH 1024
#define NIMG 2
#define NCH 8
#define HWSZ (HH * WW)
#define CHW (NCH * HWSZ)
#define PADW 1056              // halves per staged channel row (16 + 1024 + 16)
#define NBLK_MASK 2048
#define NBLK_MAIN 2048
// ws float layout: [0..2047] block mins, [2048..4095] block maxs,
// [4096] sum, [4097] cnt, [4098] ticket, diffArr at 4352
#define WS_SUM 4096
#define WS_CNT 4097
#define WS_TKT 4098
#define WS_DIFF 4352

typedef _Float16 f16x2 __attribute__((ext_vector_type(2)));
union U2 { f16x2 h; unsigned u; };
union U8 { f16x2 h[4]; float4 f; };

__device__ __forceinline__ f16x2 habs2f(f16x2 a) {
    U2 x; x.h = a; x.u &= 0x7fff7fffu; return x.h;
}
__device__ __forceinline__ f16x2 hmin2f(f16x2 a, f16x2 b) {
    U2 x, y, r; x.h = a; y.h = b;
    asm("v_pk_min_f16 %0, %1, %2" : "=v"(r.u) : "v"(x.u), "v"(y.u));
    return r.h;
}
__device__ __forceinline__ f16x2 f2h2(float a, float b) {
    f16x2 r; r.x = (_Float16)a; r.y = (_Float16)b; return r;
}

__device__ __forceinline__ int reflect_idx(int t) {
    if (t < 0) t = -t;
    if (t > HH - 1) t = 2 * (HH - 1) - t;
    return t;
}

// Pass 1: per-pixel mask diff d = |mean_c(msO) - pan|, per-block min/max (f32 exact).
template <bool STORE>
__global__ __launch_bounds__(256) void k_mask(const float* __restrict__ msO,
                                              const float* __restrict__ pan,
                                              float* __restrict__ wsF,
                                              float* __restrict__ diffArr) {
    int b = blockIdx.x;
    int gid = b * 256 + threadIdx.x;
    int base = gid * 4;
    int n = base >> 20;
    int hw = base & (HWSZ - 1);
    const float* po = msO + n * CHW + hw;
    float sx = 0.f, sy = 0.f, sz = 0.f, sw = 0.f;
#pragma unroll
    for (int c = 0; c < NCH; ++c) {
        float4 v = *(const float4*)(po + c * HWSZ);
        sx += v.x; sy += v.y; sz += v.z; sw += v.w;
    }
    float4 pv = *(const float4*)(pan + n * HWSZ + hw);
    float4 d;
    d.x = fabsf(sx * 0.125f - pv.x);
    d.y = fabsf(sy * 0.125f - pv.y);
    d.z = fabsf(sz * 0.125f - pv.z);
    d.w = fabsf(sw * 0.125f - pv.w);
    if (STORE) *(float4*)(diffArr + base) = d;

    float m = fminf(fminf(d.x, d.y), fminf(d.z, d.w));
    float M = fmaxf(fmaxf(d.x, d.y), fmaxf(d.z, d.w));
#pragma unroll
    for (int off = 32; off > 0; off >>= 1) {
        m = fminf(m, __shfl_down(m, off));
        M = fmaxf(M, __shfl_down(M, off));
    }
    __shared__ float sm[4], sM[4];
    int wid = threadIdx.x >> 6, lane = threadIdx.x & 63;
    if (lane == 0) { sm[wid] = m; sM[wid] = M; }
    __syncthreads();
    if (threadIdx.x == 0) {
        wsF[b] = fminf(fminf(sm[0], sm[1]), fminf(sm[2], sm[3]));
        wsF[2048 + b] = fmaxf(fmaxf(sM[0], sM[1]), fmaxf(sM[2], sM[3]));
        if (b == 0) {
            wsF[WS_SUM] = 0.f;
            wsF[WS_CNT] = 0.f;
            ((unsigned*)wsF)[WS_TKT] = 0u;
        }
    }
}

// Pass 2: block = 128 threads = one row; 8 px/thread; target rows staged in LDS as fp16;
// SAD accumulated in packed fp16 (v_pk ops). Epilogue: reduce mask min/max from ws,
// masked sum, ticket-based last-block finalize.
template <bool USE_DIFF>
__global__ __launch_bounds__(128, 4) void k_main(const float* __restrict__ ms,
                                                 const float* __restrict__ tgt,
                                                 const float* __restrict__ msO,
                                                 const float* __restrict__ pan,
                                                 float* __restrict__ wsF,
                                                 float* __restrict__ out) {
    __shared__ __attribute__((aligned(16))) _Float16 lds[NCH * PADW]; // 16.9 KB
    __shared__ float red[4];
    const int tid = threadIdx.x;
    // XCD-band swizzle: each XCD owns a contiguous 128-row band per image
    const int b = blockIdx.x;
    const int xcd = b & 7;
    const int idx = b >> 3;      // 0..255
    const int n = idx >> 7;      // image
    const int h = xcd * 128 + (idx & 127);
    const int w0 = tid * 8;

    // ms fragment: 8 channels x 8 px, packed fp16
    const float* msBase = ms + n * CHW + h * WW + w0;
    f16x2 msv2[8][4];
#pragma unroll
    for (int c = 0; c < NCH; ++c) {
        float4 a = *(const float4*)(msBase + c * HWSZ);
        float4 bb = *(const float4*)(msBase + c * HWSZ + 4);
        msv2[c][0] = f2h2(a.x, a.y);
        msv2[c][1] = f2h2(a.z, a.w);
        msv2[c][2] = f2h2(bb.x, bb.y);
        msv2[c][3] = f2h2(bb.z, bb.w);
    }

    // halo staging assignments (2 scalars/thread)
    int eC[2], eFidx[2], eGcol[2];
#pragma unroll
    for (int e = 0; e < 2; ++e) {
        int id = tid * 2 + e;
        eC[e] = id >> 5;
        int k = id & 31;
        if (k < 16) { eFidx[e] = k; eGcol[e] = 16 - k; }
        else        { int k2 = k - 16; eFidx[e] = 1040 + k2; eGcol[e] = 1022 - k2; }
    }

    f16x2 minv2[4];
#pragma unroll
    for (int p = 0; p < 4; ++p) minv2[p] = f2h2(3.0e4f, 3.0e4f);

    const float* tgtN = tgt + n * CHW;

    for (int di = 0; di < 9; ++di) {
        int gr = reflect_idx(h + (di - 4) * 4);
        __syncthreads(); // protect previous iteration's reads
        const float* rowBase = tgtN + gr * WW + w0;
#pragma unroll
        for (int c = 0; c < NCH; ++c) {
            float4 v0 = *(const float4*)(rowBase + c * HWSZ);
            float4 v1 = *(const float4*)(rowBase + c * HWSZ + 4);
            U8 u;
            u.h[0] = f2h2(v0.x, v0.y);
            u.h[1] = f2h2(v0.z, v0.w);
            u.h[2] = f2h2(v1.x, v1.y);
            u.h[3] = f2h2(v1.z, v1.w);
            *(float4*)&lds[c * PADW + 16 + w0] = u.f; // 16B aligned
        }
#pragma unroll
        for (int e = 0; e < 2; ++e) {
            lds[eC[e] * PADW + eFidx[e]] =
                (_Float16)tgtN[eC[e] * HWSZ + gr * WW + eGcol[e]];
        }
        __syncthreads();

        f16x2 acc2[9][4];
#pragma unroll
        for (int c = 0; c < NCH; ++c) {
            // seg: 40 halves starting at padded half-index w0 (byte 16*tid) — 16B aligned
            const float4* sp = (const float4*)&lds[c * PADW + w0];
            f16x2 seg2[20];
#pragma unroll
            for (int q = 0; q < 5; ++q) {
                U8 u;
                u.f = sp[q];
                seg2[q * 4 + 0] = u.h[0]; seg2[q * 4 + 1] = u.h[1];
                seg2[q * 4 + 2] = u.h[2]; seg2[q * 4 + 3] = u.h[3];
            }
#pragma unroll
            for (int dj = 0; dj < 9; ++dj)
#pragma unroll
                for (int p = 0; p < 4; ++p) {
                    f16x2 ab = habs2f(msv2[c][p] - seg2[dj * 2 + p]);
                    acc2[dj][p] = (c == 0) ? ab : (acc2[dj][p] + ab);
                }
        }
#pragma unroll
        for (int dj = 0; dj < 9; ++dj)
#pragma unroll
            for (int p = 0; p < 4; ++p) minv2[p] = hmin2f(minv2[p], acc2[dj][p]);
    }

    // ---- epilogue: global mask min/max from per-block values (2048 each) ----
    float lmin = 1.0e38f, lmax = -1.0e38f;
#pragma unroll
    for (int k = 0; k < 4; ++k) {
        float4 v = *(const float4*)&wsF[tid * 16 + k * 4];
        float4 w = *(const float4*)&wsF[2048 + tid * 16 + k * 4];
        lmin = fminf(lmin, fminf(fminf(v.x, v.y), fminf(v.z, v.w)));
        lmax = fmaxf(lmax, fmaxf(fmaxf(w.x, w.y), fmaxf(w.z, w.w)));
    }
#pragma unroll
    for (int off = 32; off > 0; off >>= 1) {
        lmin = fminf(lmin, __shfl_down(lmin, off));
        lmax = fmaxf(lmax, __shfl_down(lmax, off));
    }
    int wid = tid >> 6, lane = tid & 63;
    __syncthreads();
    if (lane == 0) { red[wid] = lmin; red[2 + wid] = lmax; }
    __syncthreads();
    float lo = fminf(red[0], red[1]);
    float hi = fmaxf(red[2], red[3]);
    float thresh = lo + (hi - lo) * (10.0f / 255.0f);

    float dv[8];
    if (USE_DIFF) {
        const float* dp = wsF + WS_DIFF + n * HWSZ + h * WW + w0;
        float4 a = *(const float4*)dp;
        float4 bb = *(const float4*)(dp + 4);
        dv[0] = a.x; dv[1] = a.y; dv[2] = a.z; dv[3] = a.w;
        dv[4] = bb.x; dv[5] = bb.y; dv[6] = bb.z; dv[7] = bb.w;
    } else {
        const float* po = msO + n * CHW + h * WW + w0;
        float s[8];
#pragma unroll
        for (int p = 0; p < 8; ++p) s[p] = 0.f;
#pragma unroll
        for (int c = 0; c < NCH; ++c) {
            float4 a = *(const float4*)(po + c * HWSZ);
            float4 bb = *(const float4*)(po + c * HWSZ + 4);
            s[0] += a.x; s[1] += a.y; s[2] += a.z; s[3] += a.w;
            s[4] += bb.x; s[5] += bb.y; s[6] += bb.z; s[7] += bb.w;
        }
        const float* pp = pan + n * HWSZ + h * WW + w0;
        float4 pa = *(const float4*)pp;
        float4 pb = *(const float4*)(pp + 4);
        float pvv[8] = {pa.x, pa.y, pa.z, pa.w, pb.x, pb.y, pb.z, pb.w};
#pragma unroll
        for (int p = 0; p < 8; ++p) dv[p] = fabsf(s[p] * 0.125f - pvv[p]);
    }

    float lsum = 0.f, lcnt = 0.f;
#pragma unroll
    for (int p = 0; p < 4; ++p) {
        float mvx = (float)minv2[p].x;
        float mvy = (float)minv2[p].y;
        if (dv[2 * p + 0] > thresh) { lsum += mvx; lcnt += 1.f; }
        if (dv[2 * p + 1] > thresh) { lsum += mvy; lcnt += 1.f; }
    }
#pragma unroll
    for (int off = 32; off > 0; off >>= 1) {
        lsum += __shfl_down(lsum, off);
        lcnt += __shfl_down(lcnt, off);
    }
    __syncthreads();
    if (lane == 0) { red[wid] = lsum; red[2 + wid] = lcnt; }
    __syncthreads();
    if (tid == 0) {
        atomicAdd(&wsF[WS_SUM], red[0] + red[1]);
        atomicAdd(&wsF[WS_CNT], red[2] + red[3]);
        __threadfence();
        unsigned t = atomicAdd((unsigned*)&wsF[WS_TKT], 1u);
        if (t == NBLK_MAIN - 1) { // last block: finalize
            float s = atomicAdd(&wsF[WS_SUM], 0.f);
            float c = atomicAdd(&wsF[WS_CNT], 0.f);
            out[0] = (c > 0.f) ? (s / fmaxf(c, 1.f)) : 0.f;
        }
    }
}

extern "C" void kernel_launch(void* const* d_in, const int* in_sizes, int n_in,
                              void* d_out, int out_size, void* d_ws, size_t ws_size,
                              hipStream_t stream) {
    const float* ms  = (const float*)d_in[0];
    const float* tgt = (const float*)d_in[1];
    const float* msO = (const float*)d_in[2];
    const float* pan = (const float*)d_in[3];
    float* out = (float*)d_out;
    float* wsF = (float*)d_ws;

    const size_t needWs = (size_t)(WS_DIFF + 2 * HWSZ) * 4u;
    const bool useDiff = ws_size >= needWs;

    if (useDiff) {
        k_mask<true><<<NBLK_MASK, 256, 0, stream>>>(msO, pan, wsF, wsF + WS_DIFF);
        k_main<true><<<NBLK_MAIN, 128, 0, stream>>>(ms, tgt, msO, pan, wsF, out);
    } else {
        k_mask<false><<<NBLK_MASK, 256, 0, stream>>>(msO, pan, wsF, nullptr);
        k_main<false><<<NBLK_MAIN, 128, 0, stream>>>(ms, tgt, msO, pan, wsF, out);
    }
}